// Round 3
// baseline (1353.722 us; speedup 1.0000x reference)
//
#include <hip/hip_runtime.h>
#include <hip/hip_bf16.h>
#include <stdint.h>

#define DIM 64
#define PH  64
#define TH  256
#define NN  512

typedef __attribute__((ext_vector_type(8))) short bf16x8;
typedef __attribute__((ext_vector_type(4))) float f32x4;

__device__ __forceinline__ short f2bf(float f) {
    union { float f; uint32_t u; } v; v.f = f;
    uint32_t r = v.u + 0x7fffu + ((v.u >> 16) & 1u);
    return (short)(r >> 16);
}

// Merged prep:
//  blocks [0, 4*NN):   per (b,j): q,k,v = x@w_qkv; V f32 [b,j,d]; QW1 f32 [b,j,t]; KW1t bf16 [b,t,j]
//  blocks [4*NN, +64): M[h][t] = pos_w2[h,:]@attn_w1[:,t] stored t-major bf16; cb[t] = attn_b1 + pos_b2@attn_w1
__global__ void prep_all(const float* __restrict__ x, const float* __restrict__ w_qkv,
                         const float* __restrict__ attn_w1,
                         const float* __restrict__ pos_w2, const float* __restrict__ pos_b2,
                         const float* __restrict__ attn_b1,
                         float* __restrict__ V, float* __restrict__ QW1, short* __restrict__ KW1t,
                         short* __restrict__ Mg, float* __restrict__ cbg) {
    int tid = threadIdx.x;  // 256
    if (blockIdx.x >= 4 * NN) {
        int h = blockIdx.x - 4 * NN, t = tid;
        float m = 0.f;
        for (int d = 0; d < DIM; d++) m += pos_w2[h * DIM + d] * attn_w1[d * TH + t];
        Mg[t * PH + h] = f2bf(m);
        if (h == 0) {
            float cb = attn_b1[t];
            for (int d = 0; d < DIM; d++) cb += pos_b2[d] * attn_w1[d * TH + t];
            cbg[t] = cb;
        }
        return;
    }
    int bi = blockIdx.x;
    int b = bi >> 9, j = bi & (NN - 1);
    __shared__ float xs[DIM], qs[DIM], ks[DIM];
    if (tid < DIM) xs[tid] = x[bi * DIM + tid];
    __syncthreads();
    if (tid < 3 * DIM) {
        float acc = 0.f;
        for (int e = 0; e < DIM; e++) acc += xs[e] * w_qkv[e * 3 * DIM + tid];
        if (tid < DIM) qs[tid] = acc;
        else if (tid < 2 * DIM) ks[tid - DIM] = acc;
        else V[bi * DIM + (tid - 2 * DIM)] = acc;
    }
    __syncthreads();
    float aq = 0.f, ak = 0.f;
    for (int d = 0; d < DIM; d++) {
        float w = attn_w1[d * TH + tid];
        aq += qs[d] * w; ak += ks[d] * w;
    }
    QW1[bi * TH + tid] = aq;
    KW1t[((size_t)(b * TH + tid)) * NN + j] = f2bf(ak);
}

__launch_bounds__(512, 6)
__global__ void ptl_main(const float* __restrict__ pos, const float* __restrict__ pos_w1,
                         const float* __restrict__ pos_b1, const float* __restrict__ pos_w2,
                         const float* __restrict__ pos_b2, const float* __restrict__ attn_w2,
                         const float* __restrict__ V, const float* __restrict__ QW1,
                         const short* __restrict__ KW1t, const short* __restrict__ Mg,
                         const float* __restrict__ cbg, float* __restrict__ out) {
    const int b = blockIdx.x >> 9, i = blockIdx.x & (NN - 1);
    const int tid = threadIdx.x;
    const int wv = tid >> 6, lane = tid & 63;
    const int lhi = lane >> 4, llo = lane & 15;

    __shared__ short Mlds[TH * 64];        // 32 KB, XOR-swizzled: byte = t*128 + ((seg^(t&7))<<4)
    __shared__ float posl[NN][3];
    __shared__ float2 qw2[TH];             // {QW1[i,t]+cb[t], w2[t]}
    __shared__ float4 pw4[PH];             // {pos_w1[0][h], pos_w1[1][h], pos_w1[2][h], pos_b1[h]}
    __shared__ float simbuf[NN], attnl[NN];
    __shared__ float red[64][9], redg[64][9];
    __shared__ float wmax[8], wsum[8];
    __shared__ float avl[64], gbarl[64];

    // ---- stage ----
    for (int idx = tid; idx < TH * 8; idx += 512) {   // 8 x 16B segs per 128B row, swizzled dest
        int t = idx >> 3, seg = idx & 7;
        int dstb = t * 128 + ((seg ^ (t & 7)) << 4);
        *(uint4*)((char*)Mlds + dstb) = *(const uint4*)&Mg[t * PH + seg * 8];
    }
    for (int idx = tid; idx < NN * 3; idx += 512)
        ((float*)posl)[idx] = pos[b * NN * 3 + idx];
    if (tid < TH) {
        float2 q2; q2.x = QW1[(b * NN + i) * TH + tid] + cbg[tid]; q2.y = attn_w2[tid];
        qw2[tid] = q2;
    }
    if (tid < PH) {
        float4 w; w.x = pos_w1[0 * PH + tid]; w.y = pos_w1[1 * PH + tid];
        w.z = pos_w1[2 * PH + tid]; w.w = pos_b1[tid];
        pw4[tid] = w;
    }
    __syncthreads();

    const float pi0 = posl[i][0], pi1 = posl[i][1], pi2 = posl[i][2];

    // ---- build all 8 A-fragments (4 j-tiles x K=64) in registers ----
    float r0[4], r1[4], r2[4];
    #pragma unroll
    for (int a = 0; a < 4; a++) {
        int jA = (wv + 8 * a) * 16 + llo;
        r0[a] = pi0 - posl[jA][0]; r1[a] = pi1 - posl[jA][1]; r2[a] = pi2 - posl[jA][2];
    }
    bf16x8 afr[4][2];
    #pragma unroll
    for (int kk = 0; kk < 2; kk++) {
        float g[4][8];
        #pragma unroll
        for (int e = 0; e < 8; e++) {
            float4 w = pw4[kk * 32 + lhi * 8 + e];
            #pragma unroll
            for (int a = 0; a < 4; a++)
                g[a][e] = fmaxf(r0[a] * w.x + r1[a] * w.y + r2[a] * w.z + w.w, 0.f);
        }
        #pragma unroll
        for (int a = 0; a < 4; a++) {
            #pragma unroll
            for (int e2 = 0; e2 < 4; e2++) {
                float2 p2; p2.x = g[a][2 * e2]; p2.y = g[a][2 * e2 + 1];
                union { __hip_bfloat162 h2; uint32_t u; } cv;
                cv.h2 = __float22bfloat162_rn(p2);
                ((uint32_t*)&afr[a][kk])[e2] = cv.u;
            }
        }
    }

    // ---- main loop: tt outer (shared M/qw reads), a inner ----
    float simacc[4][4] = {};
    const char* mbase = (const char*)Mlds + llo * 128;
    const int c0 = ((lhi ^ (llo & 7)) << 4);          // swizzled col for kk=0
    const int c1 = (((4 + lhi) ^ (llo & 7)) << 4);    // swizzled col for kk=1
    const short* KWb = KW1t + ((size_t)b * TH) * NN;
    #pragma unroll
    for (int tt = 0; tt < 16; tt++) {
        const int t = tt * 16 + llo;
        bf16x8 bfr0 = *(const bf16x8*)(mbase + tt * 2048 + c0);
        bf16x8 bfr1 = *(const bf16x8*)(mbase + tt * 2048 + c1);
        const float2 qw = qw2[t];
        #pragma unroll
        for (int a = 0; a < 4; a++) {
            const int jc0 = (wv + 8 * a) * 16 + lhi * 4;
            uint2 kv = *(const uint2*)(KWb + (size_t)t * NN + jc0);
            f32x4 acc = {0.f, 0.f, 0.f, 0.f};
            acc = __builtin_amdgcn_mfma_f32_16x16x32_bf16(afr[a][0], bfr0, acc, 0, 0, 0);
            acc = __builtin_amdgcn_mfma_f32_16x16x32_bf16(afr[a][1], bfr1, acc, 0, 0, 0);
            union { uint32_t u; float f; } k0, k1, k2, k3;
            k0.u = kv.x << 16; k1.u = kv.x & 0xffff0000u;
            k2.u = kv.y << 16; k3.u = kv.y & 0xffff0000u;
            simacc[a][0] += fmaxf(acc[0] + qw.x - k0.f, 0.f) * qw.y;
            simacc[a][1] += fmaxf(acc[1] + qw.x - k1.f, 0.f) * qw.y;
            simacc[a][2] += fmaxf(acc[2] + qw.x - k2.f, 0.f) * qw.y;
            simacc[a][3] += fmaxf(acc[3] + qw.x - k3.f, 0.f) * qw.y;
        }
    }
    #pragma unroll
    for (int a = 0; a < 4; a++) {
        const int jc0 = (wv + 8 * a) * 16 + lhi * 4;
        #pragma unroll
        for (int r = 0; r < 4; r++) {
            float v = simacc[a][r];
            v += __shfl_xor(v, 1); v += __shfl_xor(v, 2);
            v += __shfl_xor(v, 4); v += __shfl_xor(v, 8);
            if (llo == 0) simbuf[jc0 + r] = v;
        }
    }
    __syncthreads();

    // ---- softmax over j (one j per thread) ----
    float s = simbuf[tid];
    float mx = s;
    #pragma unroll
    for (int off = 1; off < 64; off <<= 1) mx = fmaxf(mx, __shfl_xor(mx, off));
    if (lane == 0) wmax[wv] = mx;
    __syncthreads();
    float bm = wmax[0];
    #pragma unroll
    for (int w = 1; w < 8; w++) bm = fmaxf(bm, wmax[w]);
    float p = __expf(s - bm);
    float ps = p;
    #pragma unroll
    for (int off = 1; off < 64; off <<= 1) ps += __shfl_xor(ps, off);
    if (lane == 0) wsum[wv] = ps;
    __syncthreads();
    float den = 0.f;
    #pragma unroll
    for (int w = 0; w < 8; w++) den += wsum[w];
    attnl[tid] = p / den;
    __syncthreads();

    // ---- aggregation: out = attn@V + (attn@G)@pos_w2 + pos_b2 ----
    const int d = tid & 63, grp = tid >> 6;
    const float4 wd = pw4[d];
    float av = 0.f, ag = 0.f;
    for (int jj = 0; jj < 64; jj++) {
        const int j = grp * 64 + jj;
        const float aw = attnl[j];
        av += aw * V[(b * NN + j) * DIM + d];
        float q0 = pi0 - posl[j][0], q1 = pi1 - posl[j][1], q2 = pi2 - posl[j][2];
        float g = q0 * wd.x + q1 * wd.y + q2 * wd.z + wd.w;
        ag += aw * fmaxf(g, 0.f);
    }
    red[d][grp] = av;
    redg[d][grp] = ag;
    __syncthreads();
    if (tid < 64) {
        float sv = 0.f, sg = 0.f;
        #pragma unroll
        for (int g2 = 0; g2 < 8; g2++) { sv += red[tid][g2]; sg += redg[tid][g2]; }
        avl[tid] = sv; gbarl[tid] = sg;
    }
    __syncthreads();
    if (tid < 64) {
        float o = avl[tid] + pos_b2[tid];
        for (int h = 0; h < PH; h++) o += gbarl[h] * pos_w2[h * DIM + tid];
        out[(size_t)blockIdx.x * DIM + tid] = o;
    }
}

extern "C" void kernel_launch(void* const* d_in, const int* in_sizes, int n_in,
                              void* d_out, int out_size, void* d_ws, size_t ws_size,
                              hipStream_t stream) {
    const float* x       = (const float*)d_in[0];
    const float* pos     = (const float*)d_in[1];
    const float* w_qkv   = (const float*)d_in[2];
    const float* pos_w1  = (const float*)d_in[3];
    const float* pos_b1  = (const float*)d_in[4];
    const float* pos_w2  = (const float*)d_in[5];
    const float* pos_b2  = (const float*)d_in[6];
    const float* attn_w1 = (const float*)d_in[7];
    const float* attn_b1 = (const float*)d_in[8];
    const float* attn_w2 = (const float*)d_in[9];
    // attn_b2 (d_in[10]) is softmax-invariant -> unused

    char* ws = (char*)d_ws;
    short* Mg   = (short*)(ws + 0);          //  32768 B
    float* cbg  = (float*)(ws + 32768);      //   1024 B
    float* Vw   = (float*)(ws + 33792);      // 524288 B
    float* QW1  = (float*)(ws + 558080);     // 2097152 B
    short* KW1t = (short*)(ws + 2655232);    // 1048576 B  (total ~3.6 MB)

    float* outp = (float*)d_out;

    prep_all<<<4 * NN + 64, 256, 0, stream>>>(x, w_qkv, attn_w1, pos_w2, pos_b2, attn_b1,
                                              Vw, QW1, KW1t, Mg, cbg);
    ptl_main<<<4 * NN, 512, 0, stream>>>(pos, pos_w1, pos_b1, pos_w2, pos_b2,
                                         attn_w2, Vw, QW1, KW1t, Mg, cbg, outp);
}

// Round 4
// 244.228 us; speedup vs baseline: 5.5429x; 5.5429x over previous
//
#include <hip/hip_runtime.h>
#include <hip/hip_bf16.h>
#include <stdint.h>

#define DIM 64
#define PH  64
#define TH  256
#define NN  512

typedef __attribute__((ext_vector_type(8))) short bf16x8;
typedef __attribute__((ext_vector_type(4))) float f32x4;

__device__ __forceinline__ short f2bf(float f) {
    union { float f; uint32_t u; } v; v.f = f;
    uint32_t r = v.u + 0x7fffu + ((v.u >> 16) & 1u);
    return (short)(r >> 16);
}

// Merged prep:
//  blocks [0, 4*NN):   per (b,j): q,k,v = x@w_qkv; V f32 [b,j,d]; QW1 f32 [b,j,t]; KW1t bf16 [b,t,j]
//  blocks [4*NN, +64): M[h][t] = pos_w2[h,:]@attn_w1[:,t] stored t-major bf16; cb[t] = attn_b1 + pos_b2@attn_w1
__global__ void prep_all(const float* __restrict__ x, const float* __restrict__ w_qkv,
                         const float* __restrict__ attn_w1,
                         const float* __restrict__ pos_w2, const float* __restrict__ pos_b2,
                         const float* __restrict__ attn_b1,
                         float* __restrict__ V, float* __restrict__ QW1, short* __restrict__ KW1t,
                         short* __restrict__ Mg, float* __restrict__ cbg) {
    int tid = threadIdx.x;  // 256
    if (blockIdx.x >= 4 * NN) {
        int h = blockIdx.x - 4 * NN, t = tid;
        float m = 0.f;
        for (int d = 0; d < DIM; d++) m += pos_w2[h * DIM + d] * attn_w1[d * TH + t];
        Mg[t * PH + h] = f2bf(m);
        if (h == 0) {
            float cb = attn_b1[t];
            for (int d = 0; d < DIM; d++) cb += pos_b2[d] * attn_w1[d * TH + t];
            cbg[t] = cb;
        }
        return;
    }
    int bi = blockIdx.x;
    int b = bi >> 9, j = bi & (NN - 1);
    __shared__ float xs[DIM], qs[DIM], ks[DIM];
    if (tid < DIM) xs[tid] = x[bi * DIM + tid];
    __syncthreads();
    if (tid < 3 * DIM) {
        float acc = 0.f;
        for (int e = 0; e < DIM; e++) acc += xs[e] * w_qkv[e * 3 * DIM + tid];
        if (tid < DIM) qs[tid] = acc;
        else if (tid < 2 * DIM) ks[tid - DIM] = acc;
        else V[bi * DIM + (tid - 2 * DIM)] = acc;
    }
    __syncthreads();
    float aq = 0.f, ak = 0.f;
    for (int d = 0; d < DIM; d++) {
        float w = attn_w1[d * TH + tid];
        aq += qs[d] * w; ak += ks[d] * w;
    }
    QW1[bi * TH + tid] = aq;
    KW1t[((size_t)(b * TH + tid)) * NN + j] = f2bf(ak);
}

__launch_bounds__(512, 4)   // VGPR cap 128: main loop needs ~110 live regs; (512,6) spilled to scratch (round-3 4.4GB HBM catastrophe)
__global__ void ptl_main(const float* __restrict__ pos, const float* __restrict__ pos_w1,
                         const float* __restrict__ pos_b1, const float* __restrict__ pos_w2,
                         const float* __restrict__ pos_b2, const float* __restrict__ attn_w2,
                         const float* __restrict__ V, const float* __restrict__ QW1,
                         const short* __restrict__ KW1t, const short* __restrict__ Mg,
                         const float* __restrict__ cbg, float* __restrict__ out) {
    const int b = blockIdx.x >> 9, i = blockIdx.x & (NN - 1);
    const int tid = threadIdx.x;
    const int wv = tid >> 6, lane = tid & 63;
    const int lhi = lane >> 4, llo = lane & 15;

    __shared__ short Mlds[TH * 64];        // 32 KB, XOR-swizzled: byte = t*128 + ((seg^(t&7))<<4)
    __shared__ float posl[NN][3];
    __shared__ float2 qw2[TH];             // {QW1[i,t]+cb[t], w2[t]}
    __shared__ float4 pw4[PH];             // {pos_w1[0][h], pos_w1[1][h], pos_w1[2][h], pos_b1[h]}
    __shared__ float simbuf[NN], attnl[NN];
    __shared__ float red[64][9], redg[64][9];
    __shared__ float wmax[8], wsum[8];
    __shared__ float avl[64], gbarl[64];

    // ---- stage ----
    for (int idx = tid; idx < TH * 8; idx += 512) {   // 8 x 16B segs per 128B row, swizzled dest
        int t = idx >> 3, seg = idx & 7;
        int dstb = t * 128 + ((seg ^ (t & 7)) << 4);
        *(uint4*)((char*)Mlds + dstb) = *(const uint4*)&Mg[t * PH + seg * 8];
    }
    for (int idx = tid; idx < NN * 3; idx += 512)
        ((float*)posl)[idx] = pos[b * NN * 3 + idx];
    if (tid < TH) {
        float2 q2; q2.x = QW1[(b * NN + i) * TH + tid] + cbg[tid]; q2.y = attn_w2[tid];
        qw2[tid] = q2;
    }
    if (tid < PH) {
        float4 w; w.x = pos_w1[0 * PH + tid]; w.y = pos_w1[1 * PH + tid];
        w.z = pos_w1[2 * PH + tid]; w.w = pos_b1[tid];
        pw4[tid] = w;
    }
    __syncthreads();

    const float pi0 = posl[i][0], pi1 = posl[i][1], pi2 = posl[i][2];

    // ---- build all 8 A-fragments (4 j-tiles x K=64) in registers, a-outer to limit live temps ----
    bf16x8 afr[4][2];
    #pragma unroll
    for (int a = 0; a < 4; a++) {
        const int jA = (wv + 8 * a) * 16 + llo;
        const float r0 = pi0 - posl[jA][0], r1 = pi1 - posl[jA][1], r2 = pi2 - posl[jA][2];
        #pragma unroll
        for (int kk = 0; kk < 2; kk++) {
            #pragma unroll
            for (int e2 = 0; e2 < 4; e2++) {
                float4 wA = pw4[kk * 32 + lhi * 8 + 2 * e2];
                float4 wB = pw4[kk * 32 + lhi * 8 + 2 * e2 + 1];
                float2 p2;
                p2.x = fmaxf(r0 * wA.x + r1 * wA.y + r2 * wA.z + wA.w, 0.f);
                p2.y = fmaxf(r0 * wB.x + r1 * wB.y + r2 * wB.z + wB.w, 0.f);
                union { __hip_bfloat162 h2; uint32_t u; } cv;
                cv.h2 = __float22bfloat162_rn(p2);
                ((uint32_t*)&afr[a][kk])[e2] = cv.u;
            }
        }
    }

    // ---- main loop: tt outer (shared M/qw reads), a inner ----
    float simacc[4][4] = {};
    const char* mbase = (const char*)Mlds + llo * 128;
    const int c0 = ((lhi ^ (llo & 7)) << 4);          // swizzled col for kk=0
    const int c1 = (((4 + lhi) ^ (llo & 7)) << 4);    // swizzled col for kk=1
    const short* KWb = KW1t + ((size_t)b * TH) * NN;
    #pragma unroll 4
    for (int tt = 0; tt < 16; tt++) {
        const int t = tt * 16 + llo;
        bf16x8 bfr0 = *(const bf16x8*)(mbase + tt * 2048 + c0);
        bf16x8 bfr1 = *(const bf16x8*)(mbase + tt * 2048 + c1);
        const float2 qw = qw2[t];
        #pragma unroll
        for (int a = 0; a < 4; a++) {
            const int jc0 = (wv + 8 * a) * 16 + lhi * 4;
            uint2 kv = *(const uint2*)(KWb + (size_t)t * NN + jc0);
            f32x4 acc = {0.f, 0.f, 0.f, 0.f};
            acc = __builtin_amdgcn_mfma_f32_16x16x32_bf16(afr[a][0], bfr0, acc, 0, 0, 0);
            acc = __builtin_amdgcn_mfma_f32_16x16x32_bf16(afr[a][1], bfr1, acc, 0, 0, 0);
            union { uint32_t u; float f; } k0, k1, k2, k3;
            k0.u = kv.x << 16; k1.u = kv.x & 0xffff0000u;
            k2.u = kv.y << 16; k3.u = kv.y & 0xffff0000u;
            simacc[a][0] += fmaxf(acc[0] + qw.x - k0.f, 0.f) * qw.y;
            simacc[a][1] += fmaxf(acc[1] + qw.x - k1.f, 0.f) * qw.y;
            simacc[a][2] += fmaxf(acc[2] + qw.x - k2.f, 0.f) * qw.y;
            simacc[a][3] += fmaxf(acc[3] + qw.x - k3.f, 0.f) * qw.y;
        }
    }
    #pragma unroll
    for (int a = 0; a < 4; a++) {
        const int jc0 = (wv + 8 * a) * 16 + lhi * 4;
        #pragma unroll
        for (int r = 0; r < 4; r++) {
            float v = simacc[a][r];
            v += __shfl_xor(v, 1); v += __shfl_xor(v, 2);
            v += __shfl_xor(v, 4); v += __shfl_xor(v, 8);
            if (llo == 0) simbuf[jc0 + r] = v;
        }
    }
    __syncthreads();

    // ---- softmax over j (one j per thread) ----
    float s = simbuf[tid];
    float mx = s;
    #pragma unroll
    for (int off = 1; off < 64; off <<= 1) mx = fmaxf(mx, __shfl_xor(mx, off));
    if (lane == 0) wmax[wv] = mx;
    __syncthreads();
    float bm = wmax[0];
    #pragma unroll
    for (int w = 1; w < 8; w++) bm = fmaxf(bm, wmax[w]);
    float p = __expf(s - bm);
    float ps = p;
    #pragma unroll
    for (int off = 1; off < 64; off <<= 1) ps += __shfl_xor(ps, off);
    if (lane == 0) wsum[wv] = ps;
    __syncthreads();
    float den = 0.f;
    #pragma unroll
    for (int w = 0; w < 8; w++) den += wsum[w];
    attnl[tid] = p / den;
    __syncthreads();

    // ---- aggregation: out = attn@V + (attn@G)@pos_w2 + pos_b2 ----
    const int d = tid & 63, grp = tid >> 6;
    const float4 wd = pw4[d];
    float av = 0.f, ag = 0.f;
    for (int jj = 0; jj < 64; jj++) {
        const int j = grp * 64 + jj;
        const float aw = attnl[j];
        av += aw * V[(b * NN + j) * DIM + d];
        float q0 = pi0 - posl[j][0], q1 = pi1 - posl[j][1], q2 = pi2 - posl[j][2];
        float g = q0 * wd.x + q1 * wd.y + q2 * wd.z + wd.w;
        ag += aw * fmaxf(g, 0.f);
    }
    red[d][grp] = av;
    redg[d][grp] = ag;
    __syncthreads();
    if (tid < 64) {
        float sv = 0.f, sg = 0.f;
        #pragma unroll
        for (int g2 = 0; g2 < 8; g2++) { sv += red[tid][g2]; sg += redg[tid][g2]; }
        avl[tid] = sv; gbarl[tid] = sg;
    }
    __syncthreads();
    if (tid < 64) {
        float o = avl[tid] + pos_b2[tid];
        for (int h = 0; h < PH; h++) o += gbarl[h] * pos_w2[h * DIM + tid];
        out[(size_t)blockIdx.x * DIM + tid] = o;
    }
}

extern "C" void kernel_launch(void* const* d_in, const int* in_sizes, int n_in,
                              void* d_out, int out_size, void* d_ws, size_t ws_size,
                              hipStream_t stream) {
    const float* x       = (const float*)d_in[0];
    const float* pos     = (const float*)d_in[1];
    const float* w_qkv   = (const float*)d_in[2];
    const float* pos_w1  = (const float*)d_in[3];
    const float* pos_b1  = (const float*)d_in[4];
    const float* pos_w2  = (const float*)d_in[5];
    const float* pos_b2  = (const float*)d_in[6];
    const float* attn_w1 = (const float*)d_in[7];
    const float* attn_b1 = (const float*)d_in[8];
    const float* attn_w2 = (const float*)d_in[9];
    // attn_b2 (d_in[10]) is softmax-invariant -> unused

    char* ws = (char*)d_ws;
    short* Mg   = (short*)(ws + 0);          //  32768 B
    float* cbg  = (float*)(ws + 32768);      //   1024 B
    float* Vw   = (float*)(ws + 33792);      // 524288 B
    float* QW1  = (float*)(ws + 558080);     // 2097152 B
    short* KW1t = (short*)(ws + 2655232);    // 1048576 B  (total ~3.6 MB)

    float* outp = (float*)d_out;

    prep_all<<<4 * NN + 64, 256, 0, stream>>>(x, w_qkv, attn_w1, pos_w2, pos_b2, attn_b1,
                                              Vw, QW1, KW1t, Mg, cbg);
    ptl_main<<<4 * NN, 512, 0, stream>>>(pos, pos_w1, pos_b1, pos_w2, pos_b2,
                                         attn_w2, Vw, QW1, KW1t, Mg, cbg, outp);
}

// Round 7
// 210.628 us; speedup vs baseline: 6.4271x; 1.1595x over previous
//
#include <hip/hip_runtime.h>
#include <hip/hip_bf16.h>
#include <stdint.h>

#define DIM 64
#define TH  256
#define NN  512
#define IB  4            // queries (i) per main block

typedef __attribute__((ext_vector_type(8))) short bf16x8;
typedef __attribute__((ext_vector_type(4))) float f32x4;

__device__ __forceinline__ short f2bf(float f) {
    union { float f; uint32_t u; } v; v.f = f;
    uint32_t r = v.u + 0x7fffu + ((v.u >> 16) & 1u);
    return (short)(r >> 16);
}

// prep:
//  bid < 256:  8 j's per block: qkv = x@w_qkv; V f32 [b,j,d]; Kneg bf16 [b,j,d] = -k; QW1 f32 [b,j,t]
//  bid >= 256: 8 blocks build Bext bf16 [256 t][128 k] (k<64: M[h,t]=pos_w2@W1; k>=64: W1[d,t]) + cb[t]
__global__ void prep_all(const float* __restrict__ x, const float* __restrict__ w_qkv,
                         const float* __restrict__ attn_w1,
                         const float* __restrict__ pos_w2, const float* __restrict__ pos_b2,
                         const float* __restrict__ attn_b1,
                         float* __restrict__ V, float* __restrict__ QW1, short* __restrict__ Kneg,
                         short* __restrict__ Bg, float* __restrict__ cbg) {
    const int tid = threadIdx.x;  // 256
    if (blockIdx.x >= 256) {
        // Bext: 8 blocks x 32 t each; thread = (t_local = tid>>3, octet = tid&7)
        const int t = (blockIdx.x - 256) * 32 + (tid >> 3);
        const int h0 = (tid & 7) * 8;
        #pragma unroll
        for (int hh = 0; hh < 8; hh++) {
            int h = h0 + hh;
            float m = 0.f;
            for (int d = 0; d < DIM; d++) m += pos_w2[h * DIM + d] * attn_w1[d * TH + t];
            Bg[t * 128 + h] = f2bf(m);
            Bg[t * 128 + 64 + h] = f2bf(attn_w1[h * TH + t]);
        }
        if ((tid & 7) == 0) {
            float cb = attn_b1[t];
            for (int d = 0; d < DIM; d++) cb += pos_b2[d] * attn_w1[d * TH + t];
            cbg[t] = cb;
        }
        return;
    }
    const int b = blockIdx.x >> 6, j0 = (blockIdx.x & 63) * 8;
    __shared__ float xs[8][DIM], qs[8][DIM];
    #pragma unroll
    for (int p = 0; p < 2; p++) {
        int idx = tid + p * 256;
        xs[idx >> 6][idx & 63] = x[(size_t)(b * NN + j0) * DIM + idx];
    }
    __syncthreads();
    if (tid < 192) {
        for (int jj = 0; jj < 8; jj++) {
            float acc = 0.f;
            for (int e = 0; e < DIM; e++) acc += xs[jj][e] * w_qkv[e * 192 + tid];
            size_t row = (size_t)(b * NN + j0 + jj) * DIM;
            if (tid < 64)       qs[jj][tid] = acc;
            else if (tid < 128) Kneg[row + (tid - 64)] = f2bf(-acc);
            else                V[row + (tid - 128)] = acc;
        }
    }
    __syncthreads();
    for (int jj = 0; jj < 8; jj++) {
        float aq = 0.f;
        for (int d = 0; d < DIM; d++) aq += qs[jj][d] * attn_w1[d * TH + tid];
        QW1[(size_t)(b * NN + j0 + jj) * TH + tid] = aq;
    }
}

__launch_bounds__(512, 2)   // cap 256 VGPR; ~120 live in main loop. (512,6) caused the round-3 spill disaster.
__global__ void ptl_main(const float* __restrict__ pos, const float* __restrict__ pos_w1,
                         const float* __restrict__ pos_b1, const float* __restrict__ pos_w2,
                         const float* __restrict__ pos_b2, const float* __restrict__ attn_w2,
                         const float* __restrict__ V, const float* __restrict__ QW1,
                         const short* __restrict__ Kneg, const short* __restrict__ Bg,
                         const float* __restrict__ cbg, float* __restrict__ out) {
    const int b = blockIdx.x >> 7, i0 = (blockIdx.x & 127) * IB;
    const int tid = threadIdx.x;
    const int wv = tid >> 6, lane = tid & 63;
    const int lhi = lane >> 4, llo = lane & 15;

    __shared__ __align__(16) short Blds[TH * 128];   // 64KB: row t (256B = 16 segs), seg s at ((s^(t&15))<<4)
    __shared__ float posl[NN][3];                    // 6144
    __shared__ float2 qwl[IB][TH];                   // 8192: {QW1[i,t]+cb[t], w2[t]}
    __shared__ float4 pw4[DIM];                      // 1024: {pos_w1[0..2][h], pos_b1[h]}
    __shared__ float simbuf[IB][NN];                 // 8192 (reused as attn)
    __shared__ float aggw[8][IB][2][DIM];            // 16384
    __shared__ float fin[IB][2][DIM];                // 2048
    __shared__ float wred[2][IB][8];                 // max / sum partials

    // ---- stage ----
    for (int idx = tid; idx < TH * 16; idx += 512) {         // 4096 16B segs
        int t = idx >> 4, s = idx & 15;
        *(uint4*)((char*)Blds + t * 256 + ((s ^ (t & 15)) << 4)) =
            *(const uint4*)((const char*)Bg + (size_t)idx * 16);
    }
    for (int idx = tid; idx < NN * 3; idx += 512)
        ((float*)posl)[idx] = pos[b * NN * 3 + idx];
    if (tid < TH) {
        float w2 = attn_w2[tid], cb = cbg[tid];
        #pragma unroll
        for (int ii = 0; ii < IB; ii++) {
            float2 q2; q2.x = QW1[(size_t)(b * NN + i0 + ii) * TH + tid] + cb; q2.y = w2;
            qwl[ii][tid] = q2;
        }
    }
    if (tid < DIM) {
        float4 w; w.x = pos_w1[tid]; w.y = pos_w1[DIM + tid];
        w.z = pos_w1[2 * DIM + tid]; w.w = pos_b1[tid];
        pw4[tid] = w;
    }
    // Kneg fragments: i-invariant, held in regs for the whole kernel (global, no barrier dep)
    bf16x8 knf[4][2];
    #pragma unroll
    for (int jt = 0; jt < 4; jt++) {
        size_t row = (size_t)(b * NN + wv * 64 + jt * 16 + llo) * DIM;
        knf[jt][0] = *(const bf16x8*)(Kneg + row + lhi * 8);
        knf[jt][1] = *(const bf16x8*)(Kneg + row + 32 + lhi * 8);
    }
    __syncthreads();

    const char* mb = (const char*)Blds + llo * 256;
    const int s0 = ((0  + lhi) ^ llo) << 4;
    const int s1 = ((4  + lhi) ^ llo) << 4;
    const int s2 = ((8  + lhi) ^ llo) << 4;
    const int s3 = ((12 + lhi) ^ llo) << 4;

    // ---- main: per i, sim over this wave's 64-j range, K=128 MFMA ----
    #pragma unroll 1
    for (int ii = 0; ii < IB; ii++) {
        const float pi0 = posl[i0 + ii][0], pi1 = posl[i0 + ii][1], pi2 = posl[i0 + ii][2];
        bf16x8 gfr[4][2];
        #pragma unroll
        for (int jt = 0; jt < 4; jt++) {
            const int jA = wv * 64 + jt * 16 + llo;
            const float r0 = pi0 - posl[jA][0], r1 = pi1 - posl[jA][1], r2 = pi2 - posl[jA][2];
            #pragma unroll
            for (int kk = 0; kk < 2; kk++) {
                #pragma unroll
                for (int e2 = 0; e2 < 4; e2++) {
                    float4 wA = pw4[kk * 32 + lhi * 8 + 2 * e2];
                    float4 wB = pw4[kk * 32 + lhi * 8 + 2 * e2 + 1];
                    float2 p2;
                    p2.x = fmaxf(r0 * wA.x + r1 * wA.y + r2 * wA.z + wA.w, 0.f);
                    p2.y = fmaxf(r0 * wB.x + r1 * wB.y + r2 * wB.z + wB.w, 0.f);
                    union { __hip_bfloat162 h2; uint32_t u; } cv;
                    cv.h2 = __float22bfloat162_rn(p2);
                    ((uint32_t*)&gfr[jt][kk])[e2] = cv.u;
                }
            }
        }
        float sa[4][4] = {};
        #pragma unroll 4
        for (int tt = 0; tt < 16; tt++) {
            const int t = tt * 16 + llo;
            bf16x8 bf0 = *(const bf16x8*)(mb + tt * 4096 + s0);
            bf16x8 bf1 = *(const bf16x8*)(mb + tt * 4096 + s1);
            bf16x8 bf2 = *(const bf16x8*)(mb + tt * 4096 + s2);
            bf16x8 bf3 = *(const bf16x8*)(mb + tt * 4096 + s3);
            const float2 qw = qwl[ii][t];
            #pragma unroll
            for (int jt = 0; jt < 4; jt++) {
                f32x4 acc = {0.f, 0.f, 0.f, 0.f};
                acc = __builtin_amdgcn_mfma_f32_16x16x32_bf16(gfr[jt][0], bf0, acc, 0, 0, 0);
                acc = __builtin_amdgcn_mfma_f32_16x16x32_bf16(gfr[jt][1], bf1, acc, 0, 0, 0);
                acc = __builtin_amdgcn_mfma_f32_16x16x32_bf16(knf[jt][0], bf2, acc, 0, 0, 0);
                acc = __builtin_amdgcn_mfma_f32_16x16x32_bf16(knf[jt][1], bf3, acc, 0, 0, 0);
                #pragma unroll
                for (int r = 0; r < 4; r++)
                    sa[jt][r] += fmaxf(acc[r] + qw.x, 0.f) * qw.y;
            }
        }
        #pragma unroll
        for (int jt = 0; jt < 4; jt++) {
            #pragma unroll
            for (int r = 0; r < 4; r++) {
                float v = sa[jt][r];
                v += __shfl_xor(v, 1); v += __shfl_xor(v, 2);
                v += __shfl_xor(v, 4); v += __shfl_xor(v, 8);
                if (llo == 0) simbuf[ii][wv * 64 + jt * 16 + lhi * 4 + r] = v;
            }
        }
    }
    __syncthreads();

    // ---- softmax per i over j (thread = j) ----
    float sv[IB];
    #pragma unroll
    for (int ii = 0; ii < IB; ii++) {
        float s = simbuf[ii][tid];
        sv[ii] = s;
        float mx = s;
        #pragma unroll
        for (int off = 1; off < 64; off <<= 1) mx = fmaxf(mx, __shfl_xor(mx, off));
        if (lane == 0) wred[0][ii][wv] = mx;
    }
    __syncthreads();
    float pv[IB];
    #pragma unroll
    for (int ii = 0; ii < IB; ii++) {
        float bm = wred[0][ii][0];
        #pragma unroll
        for (int w = 1; w < 8; w++) bm = fmaxf(bm, wred[0][ii][w]);
        float p = __expf(sv[ii] - bm);
        pv[ii] = p;
        float ps = p;
        #pragma unroll
        for (int off = 1; off < 64; off <<= 1) ps += __shfl_xor(ps, off);
        if (lane == 0) wred[1][ii][wv] = ps;
    }
    __syncthreads();
    #pragma unroll
    for (int ii = 0; ii < IB; ii++) {
        float den = 0.f;
        #pragma unroll
        for (int w = 0; w < 8; w++) den += wred[1][ii][w];
        simbuf[ii][tid] = pv[ii] / den;    // attn
    }
    __syncthreads();

    // ---- aggregation: out = attn@V + (attn@G)@pos_w2 + pos_b2; wave handles its j-range, lane = d/h ----
    {
        const int d = lane;
        const float4 wd = pw4[d];
        float pia[IB][3];
        #pragma unroll
        for (int ii = 0; ii < IB; ii++) {
            pia[ii][0] = posl[i0 + ii][0]; pia[ii][1] = posl[i0 + ii][1]; pia[ii][2] = posl[i0 + ii][2];
        }
        float av[IB] = {}, ag[IB] = {};
        const float* vb = V + (size_t)(b * NN + wv * 64) * DIM + d;
        #pragma unroll 4
        for (int jj = 0; jj < 64; jj++) {
            const int j = wv * 64 + jj;
            const float vv = vb[jj * DIM];
            const float p0 = posl[j][0], p1 = posl[j][1], p2 = posl[j][2];
            #pragma unroll
            for (int ii = 0; ii < IB; ii++) {
                const float a = simbuf[ii][j];
                av[ii] += a * vv;
                float g = (pia[ii][0] - p0) * wd.x + (pia[ii][1] - p1) * wd.y +
                          (pia[ii][2] - p2) * wd.z + wd.w;
                ag[ii] += a * fmaxf(g, 0.f);
            }
        }
        #pragma unroll
        for (int ii = 0; ii < IB; ii++) {
            aggw[wv][ii][0][d] = av[ii];
            aggw[wv][ii][1][d] = ag[ii];
        }
    }
    __syncthreads();
    {   // reduce over 8 waves: one elem per thread (IB*2*64 = 512)
        const int ii = tid >> 7, pp = (tid >> 6) & 1, d2 = tid & 63;
        float s = 0.f;
        #pragma unroll
        for (int w = 0; w < 8; w++) s += aggw[w][ii][pp][d2];
        fin[ii][pp][d2] = s;
    }
    __syncthreads();
    if (tid < IB * DIM) {
        const int ii = tid >> 6, d2 = tid & 63;
        float o = fin[ii][0][d2] + pos_b2[d2];
        for (int h = 0; h < DIM; h++) o += fin[ii][1][h] * pos_w2[h * DIM + d2];
        out[(size_t)(b * NN + i0 + ii) * DIM + d2] = o;
    }
}

extern "C" void kernel_launch(void* const* d_in, const int* in_sizes, int n_in,
                              void* d_out, int out_size, void* d_ws, size_t ws_size,
                              hipStream_t stream) {
    const float* x       = (const float*)d_in[0];
    const float* pos     = (const float*)d_in[1];
    const float* w_qkv   = (const float*)d_in[2];
    const float* pos_w1  = (const float*)d_in[3];
    const float* pos_b1  = (const float*)d_in[4];
    const float* pos_w2  = (const float*)d_in[5];
    const float* pos_b2  = (const float*)d_in[6];
    const float* attn_w1 = (const float*)d_in[7];
    const float* attn_b1 = (const float*)d_in[8];
    const float* attn_w2 = (const float*)d_in[9];
    // attn_b2 (d_in[10]) is softmax-invariant -> unused

    char* ws = (char*)d_ws;
    short* Bg   = (short*)(ws + 0);          //  65536 B  Bext bf16 [256][128]
    float* cbg  = (float*)(ws + 65536);      //   1024 B
    float* Vw   = (float*)(ws + 66560);      // 524288 B  V f32
    float* QW1  = (float*)(ws + 590848);     // 2097152 B q@W1 f32
    short* Kneg = (short*)(ws + 2688000);    // 262144 B  -k bf16   (total ~2.95 MB)

    float* outp = (float*)d_out;

    prep_all<<<264, 256, 0, stream>>>(x, w_qkv, attn_w1, pos_w2, pos_b2, attn_b1,
                                      Vw, QW1, Kneg, Bg, cbg);
    ptl_main<<<4 * (NN / IB), 512, 0, stream>>>(pos, pos_w1, pos_b1, pos_w2, pos_b2,
                                                attn_w2, Vw, QW1, Kneg, Bg, cbg, outp);
}